// Round 7
// baseline (275.790 us; speedup 1.0000x reference)
//
#include <hip/hip_runtime.h>
#include <hip/hip_bf16.h>
#include <stdint.h>

typedef float f32x4 __attribute__((ext_vector_type(4)));
typedef __bf16 bf16x8 __attribute__((ext_vector_type(8)));
typedef unsigned short ushort8 __attribute__((ext_vector_type(8)));

#define NB 8
#define NS 8192
#define ND 512
#define NM (NB * NS)      // 65536 rows
#define NK 512            // reduction dim

// ---------------- helpers ----------------
__device__ __forceinline__ unsigned short f2bf(float f) {
  unsigned u = __float_as_uint(f);
  u += 0x7FFFu + ((u >> 16) & 1u);
  return (unsigned short)(u >> 16);
}

// packed f32x2 -> bf16x2 (RNE), low = a, high = b
__device__ __forceinline__ uint32_t cvtpk(float lo, float hi) {
  uint32_t r;
  asm("v_cvt_pk_bf16_f32 %0, %1, %2" : "=v"(r) : "v"(lo), "v"(hi));
  return r;
}

__global__ __launch_bounds__(256) void cvt_bf16(const float* __restrict__ src,
                                                unsigned short* __restrict__ dst,
                                                int n8) {
  int i = blockIdx.x * 256 + threadIdx.x;
  if (i >= n8) return;
  const float4* s = reinterpret_cast<const float4*>(src + (size_t)i * 8);
  float4 v0 = s[0], v1 = s[1];
  ushort8 o;
  o[0] = f2bf(v0.x); o[1] = f2bf(v0.y); o[2] = f2bf(v0.z); o[3] = f2bf(v0.w);
  o[4] = f2bf(v1.x); o[5] = f2bf(v1.y); o[6] = f2bf(v1.z); o[7] = f2bf(v1.w);
  *reinterpret_cast<ushort8*>(dst + (size_t)i * 8) = o;
}

// ---------------- fused GEMM + a/b epilogue + chunk-aggregate ----------------
// Block: 128 seq rows (= one scan chunk) x (64 hidden + matching 64 gate cols).
// A staged from f32 x directly: global f32 -> cvt_pk bf16 -> swizzled ds_write
// (kills the separate cvt_x pass). B staged via global_load_lds (bf16 W).
// 2-phase double-buffered schedule (R6 structure). Epilogue: computes packed
// (a,b) bf16 pairs AND the per-chunk affine aggregate (A_c,B_c) in-register
// (kills scan_pass1). T1 XCD grid swizzle, T2 XOR LDS swizzle.
__global__ __launch_bounds__(256) void gemm_ab(const float* __restrict__ x,
                                               const unsigned short* __restrict__ wb,
                                               uint32_t* __restrict__ pk,
                                               float* __restrict__ aggA,
                                               float* __restrict__ aggB) {
  __shared__ __align__(16) unsigned short lds[2 * 2 * 128 * 64]; // buf{0,1} x (A|B), 64KB
  float* gbuf = reinterpret_cast<float*>(lds);                   // 32KB alias (epilogue)
  float* aggL = reinterpret_cast<float*>((char*)lds + 32768);    // 512B (cross-wave agg)

  const int tid = threadIdx.x;
  const int w = tid >> 6;
  const int lane = tid & 63;
  const int wr = w >> 1;          // row-half
  const int wc = w & 1;           // 0: hidden cols, 1: gate cols
  // T1 bijective XCD swizzle: 4096 = 512 mblk x 8 nblk
  const int orig = blockIdx.x;
  const int wg = (orig & 7) * 512 + (orig >> 3);
  const int mblk = wg >> 3;
  const int nblk = wg & 7;
  const int m0 = mblk * 128;
  const int n0 = nblk * 64;

  const int lrow = lane >> 3;                    // 0..7
  const int c0f = (lane & 7) * 8;                // natural f32 col for A reg-stage
  const int lcol = (((lane & 7) ^ lrow) * 8);    // pre-swizzled source col for B

  // A: global f32 -> registers (issued early, consumed by writeA)
  float4 aR[4][2];
  auto loadA = [&](int kt) {
    const int k0 = kt << 6;
#pragma unroll
    for (int i = 0; i < 4; ++i) {
      int row = i * 32 + w * 8 + lrow;
      const float* src = x + (size_t)(m0 + row) * NK + k0 + c0f;
      aR[i][0] = *reinterpret_cast<const float4*>(src);
      aR[i][1] = *reinterpret_cast<const float4*>(src + 4);
    }
  };
  // cvt + swizzled ds_write_b128 into buffer's A half
  auto writeA = [&](int buf) {
    char* base = (char*)(lds + buf * 16384);
#pragma unroll
    for (int i = 0; i < 4; ++i) {
      int row = i * 32 + w * 8 + lrow;
      uint4 q;
      q.x = cvtpk(aR[i][0].x, aR[i][0].y);
      q.y = cvtpk(aR[i][0].z, aR[i][0].w);
      q.z = cvtpk(aR[i][1].x, aR[i][1].y);
      q.w = cvtpk(aR[i][1].z, aR[i][1].w);
      int off = row * 128 + (((lane & 7) * 16) ^ (lrow << 4));
      *reinterpret_cast<uint4*>(base + off) = q;
    }
  };
  // B: global_load_lds, pre-swizzled source, linear dest
  auto stageB = [&](int buf, int kt) {
    const int k0 = kt << 6;
    unsigned short* base = lds + buf * 16384 + 8192;
#pragma unroll
    for (int i = 0; i < 4; ++i) {
      int row = i * 32 + w * 8 + lrow;
      int e = (row < 64) ? (n0 + row) : (448 + n0 + row);
      const unsigned short* srcB = wb + (size_t)e * NK + k0 + lcol;
      __builtin_amdgcn_global_load_lds(
          (const __attribute__((address_space(1))) void*)srcB,
          (__attribute__((address_space(3))) void*)(base + i * 2048 + w * 512),
          16, 0, 0);
    }
  };

  f32x4 acc[4][4];
#pragma unroll
  for (int i = 0; i < 4; ++i)
#pragma unroll
    for (int j = 0; j < 4; ++j) acc[i][j] = (f32x4)0.0f;

  const int fr = lane & 15;
  const int kg = lane >> 4;

  // prologue: stage kt0 -> buf0
  loadA(0);
  stageB(0, 0);
  writeA(0);          // compiler inserts vmcnt waits for aR
  __syncthreads();    // drains B gload_lds + ds_writes

#pragma unroll 1
  for (int kt = 0; kt < 8; ++kt) {
    const int cur = kt & 1;
    if (kt < 7) { loadA(kt + 1); stageB(cur ^ 1, kt + 1); }  // issue early

    const char* ldsA = (const char*)(lds + cur * 16384);
    const char* ldsB = ldsA + 16384;
#pragma unroll
    for (int kk = 0; kk < 64; kk += 32) {
      bf16x8 af[4], bfr[4];
#pragma unroll
      for (int i = 0; i < 4; ++i) {
        int rowA = wr * 64 + i * 16 + fr;
        int swzA = (kk * 2 + kg * 16) ^ ((rowA & 7) << 4);
        af[i] = *reinterpret_cast<const bf16x8*>(ldsA + rowA * 128 + swzA);
        int rowB = wc * 64 + i * 16 + fr;
        int swzB = (kk * 2 + kg * 16) ^ ((rowB & 7) << 4);
        bfr[i] = *reinterpret_cast<const bf16x8*>(ldsB + rowB * 128 + swzB);
      }
#pragma unroll
      for (int i = 0; i < 4; ++i)
#pragma unroll
        for (int j = 0; j < 4; ++j)
          acc[i][j] = __builtin_amdgcn_mfma_f32_16x16x32_bf16(af[i], bfr[j], acc[i][j], 0, 0, 0);
    }
    if (kt < 7) writeA(cur ^ 1);   // write-late: aR landed during MFMA phase
    __syncthreads();               // drains loads + ds ops, orders buffers
  }

  // ---------------- epilogue ----------------
  // gate waves publish gate values to LDS (swizzled); hidden waves fuse a,b,
  // store packed (a|b<<16), and build the chunk affine aggregate.
  if (wc == 1) {
#pragma unroll
    for (int i = 0; i < 4; ++i)
#pragma unroll
      for (int j = 0; j < 4; ++j)
#pragma unroll
        for (int r = 0; r < 4; ++r) {
          int row = wr * 64 + i * 16 + kg * 4 + r;
          int dl = j * 16 + fr;
          int dsw = dl ^ (((row >> 2) & 3) << 4);
          gbuf[row * 64 + dsw] = acc[i][j][r];
        }
  }
  __syncthreads();

  float A64[4], B64[4];
  if (wc == 0) {
#pragma unroll
    for (int j = 0; j < 4; ++j) {
      float Ai[4], Bi[4];
#pragma unroll
      for (int i = 0; i < 4; ++i) {
        float As = 1.0f, Bs = 0.0f;
#pragma unroll
        for (int r = 0; r < 4; ++r) {
          int row = wr * 64 + i * 16 + kg * 4 + r;
          int dl = j * 16 + fr;
          int dsw = dl ^ (((row >> 2) & 3) << 4);
          float hid = acc[i][j][r];
          float gat = gbuf[row * 64 + dsw];
          float a = 1.0f / (1.0f + __expf(gat));     // sigmoid(-gate)
          float z = 1.0f - a;                        // sigmoid(gate)
          float g = (hid >= 0.0f) ? (hid + 0.5f) : (1.0f / (1.0f + __expf(-hid)));
          float bb = z * g;
          pk[(size_t)(m0 + row) * ND + n0 + dl] =
              ((uint32_t)f2bf(bb) << 16) | (uint32_t)f2bf(a);
          Bs = fmaf(a, Bs, bb);   // ordered: r ascending
          As *= a;
        }
        Ai[i] = As; Bi[i] = Bs;
      }
      // ordered affine composition across kg (rows kg*4.. within each 16-row group)
#pragma unroll
      for (int i = 0; i < 4; ++i) {
        float pA = __shfl_xor(Ai[i], 16);
        float pB = __shfl_xor(Bi[i], 16);
        Bi[i] = (kg & 1) ? fmaf(Ai[i], pB, Bi[i]) : fmaf(pA, Bi[i], pB);
        Ai[i] *= pA;
        pA = __shfl_xor(Ai[i], 32);
        pB = __shfl_xor(Bi[i], 32);
        Bi[i] = (kg & 2) ? fmaf(Ai[i], pB, Bi[i]) : fmaf(pA, Bi[i], pB);
        Ai[i] *= pA;
      }
      // serial over i (16-row groups, ascending)
      float As = Ai[0], Bs = Bi[0];
#pragma unroll
      for (int i = 1; i < 4; ++i) { Bs = fmaf(Ai[i], Bs, Bi[i]); As *= Ai[i]; }
      A64[j] = As; B64[j] = Bs;
    }
    if (wr == 0 && kg == 0) {
#pragma unroll
      for (int j = 0; j < 4; ++j) {
        int ch = j * 16 + fr;
        aggL[ch * 2] = A64[j];
        aggL[ch * 2 + 1] = B64[j];
      }
    }
  }
  __syncthreads();
  if (wc == 0 && wr == 1 && kg == 0) {
#pragma unroll
    for (int j = 0; j < 4; ++j) {
      int ch = j * 16 + fr;
      float A0 = aggL[ch * 2], B0 = aggL[ch * 2 + 1];
      size_t o = (size_t)mblk * ND + n0 + ch;     // mblk == global chunk index
      aggA[o] = A0 * A64[j];
      aggB[o] = fmaf(A64[j], B0, B64[j]);
    }
  }
}

// ---------------- scan pass2: prefix + rescan, write out f32 ----------------
__global__ __launch_bounds__(256) void scan_pass2(const uint32_t* __restrict__ pk,
                                                  const float* __restrict__ aggA,
                                                  const float* __restrict__ aggB,
                                                  float* __restrict__ out,
                                                  float* __restrict__ nextp) {
  int bid = blockIdx.x;
  int b = bid >> 6;
  int c = bid & 63;
  int d2 = threadIdx.x;        // channel-pair 0..255

  float h0 = 0.0f, h1 = 0.0f;
  for (int cc = 0; cc < c; ++cc) {
    int o = (b * 64 + cc) * ND + d2 * 2;
    float2 Aa = *reinterpret_cast<const float2*>(&aggA[o]);
    float2 Bb = *reinterpret_cast<const float2*>(&aggB[o]);
    h0 = fmaf(Aa.x, h0, Bb.x);
    h1 = fmaf(Aa.y, h1, Bb.y);
  }
  size_t base = (size_t)(b * NS + c * 128) * ND + d2 * 2;
#pragma unroll 4
  for (int t = 0; t < 128; ++t) {
    size_t idx = base + (size_t)t * ND;
    uint2 v = *reinterpret_cast<const uint2*>(pk + idx);
    float a0 = __uint_as_float(v.x << 16);
    float b0 = __uint_as_float(v.x & 0xffff0000u);
    float a1 = __uint_as_float(v.y << 16);
    float b1 = __uint_as_float(v.y & 0xffff0000u);
    h0 = fmaf(a0, h0, b0);
    h1 = fmaf(a1, h1, b1);
    *reinterpret_cast<float2*>(&out[idx]) = make_float2(h0, h1);
  }
  if (c == 63) {
    *reinterpret_cast<float2*>(&nextp[b * ND + d2 * 2]) = make_float2(h0, h1);
  }
}

// ---------------- launcher ----------------
extern "C" void kernel_launch(void* const* d_in, const int* in_sizes, int n_in,
                              void* d_out, int out_size, void* d_ws, size_t ws_size,
                              hipStream_t stream) {
  const float* x = (const float*)d_in[0];   // (8, 8192, 512) f32
  const float* W = (const float*)d_in[1];   // (1024, 512) f32
  float* out = (float*)d_out;               // 33554432 + 4096 f32

  char* ws = (char*)d_ws;
  uint32_t* pk = (uint32_t*)ws;                                            // 128 MB
  unsigned short* wbf = (unsigned short*)(ws + (size_t)128 * 1024 * 1024); // 1 MB
  float* aggA = (float*)(ws + (size_t)129 * 1024 * 1024);                  // 1 MB
  float* aggB = (float*)(ws + (size_t)130 * 1024 * 1024);                  // 1 MB
  float* nextp = out + (size_t)NM * ND;

  cvt_bf16<<<256, 256, 0, stream>>>(W, wbf, (1024 * NK) / 8);
  gemm_ab<<<4096, 256, 0, stream>>>(x, wbf, pk, aggA, aggB);
  scan_pass2<<<512, 256, 0, stream>>>(pk, aggA, aggB, out, nextp);
}